// Round 1
// baseline (2094.351 us; speedup 1.0000x reference)
//
#include <hip/hip_runtime.h>
#include <hip/hip_bf16.h>
#include <math.h>

#define N_NODES 100000
#define N_EDGES 1000000
#define N_GRAPHS 100
#define IN_F 128
#define HID 64
#define N_CLS 40
#define EPS 1e-5f
#define SB 512   // stats partial blocks

__device__ __forceinline__ float gelu_exact(float x) {
    return 0.5f * x * (1.0f + erff(x * 0.70710678118654752f));
}

// ---------------- degrees ----------------
__global__ void k_degree(const int* __restrict__ src, const int* __restrict__ dst,
                         float* __restrict__ deg_out, float* __restrict__ deg_in) {
    int i = blockIdx.x * blockDim.x + threadIdx.x;
    if (i < N_EDGES) {
        atomicAdd(&deg_out[src[i]], 1.0f);
        atomicAdd(&deg_in[dst[i]], 1.0f);
    }
}

__global__ void k_dn(float* __restrict__ d) {  // in-place deg -> deg^-0.5 (2*N_NODES)
    int i = blockIdx.x * blockDim.x + threadIdx.x;
    if (i < 2 * N_NODES) {
        float v = d[i];
        d[i] = 1.0f / sqrtf(v > 0.0f ? v : 1.0f);
    }
}

// ---------------- layer0 fused GEMM: h0 = dn_out*(x@W0), res0 = gelu(x@Wr0+br0) ----------------
__global__ __launch_bounds__(256) void k_gemm0(
    const float* __restrict__ x, const float* __restrict__ W0,
    const float* __restrict__ Wr0, const float* __restrict__ br0,
    const float* __restrict__ dn_out,
    float* __restrict__ h0, float* __restrict__ res0)
{
    __shared__ float ws[64][128];   // half-K of [W0|Wr0], 32KB
    __shared__ float xs[32][132];   // 32 rows of x, padded, ~16.9KB
    int t = threadIdx.x;
    int row0 = blockIdx.x * 32;

    // stage x tile: 32 rows * 32 float4
    for (int i = 0; i < 4; ++i) {
        int j = t + i * 256;
        int r = j >> 5, kq = j & 31;
        float4 v = *(const float4*)(x + (size_t)(row0 + r) * IN_F + kq * 4);
        *(float4*)(&xs[r][kq * 4]) = v;
    }

    int tr = t >> 5, tc = t & 31;  // 8 row-groups x 32 col-groups
    float acc[4][4] = {};

    for (int kh = 0; kh < 2; ++kh) {
        __syncthreads();
        // stage weights for k in [kh*64, kh*64+64): 8192 elems
        for (int i = 0; i < 32; ++i) {
            int idx = t + i * 256;
            int k = idx >> 7, c = idx & 127;
            int kg = kh * 64 + k;
            ws[k][c] = (c < 64) ? W0[kg * 64 + c] : Wr0[kg * 64 + (c - 64)];
        }
        __syncthreads();
        for (int k = 0; k < 64; ++k) {
            float4 w = *(const float4*)(&ws[k][tc * 4]);
            int kk = kh * 64 + k;
            float a0 = xs[tr * 4 + 0][kk];
            float a1 = xs[tr * 4 + 1][kk];
            float a2 = xs[tr * 4 + 2][kk];
            float a3 = xs[tr * 4 + 3][kk];
            acc[0][0] += a0 * w.x; acc[0][1] += a0 * w.y; acc[0][2] += a0 * w.z; acc[0][3] += a0 * w.w;
            acc[1][0] += a1 * w.x; acc[1][1] += a1 * w.y; acc[1][2] += a1 * w.z; acc[1][3] += a1 * w.w;
            acc[2][0] += a2 * w.x; acc[2][1] += a2 * w.y; acc[2][2] += a2 * w.z; acc[2][3] += a2 * w.w;
            acc[3][0] += a3 * w.x; acc[3][1] += a3 * w.y; acc[3][2] += a3 * w.z; acc[3][3] += a3 * w.w;
        }
    }

    // epilogue
    int cbase = tc * 4;
    for (int i = 0; i < 4; ++i) {
        int R = row0 + tr * 4 + i;
        float dn = dn_out[R];
        for (int j = 0; j < 4; ++j) {
            int c = cbase + j;
            if (c < 64) {
                h0[(size_t)R * 64 + c] = dn * acc[i][j];
            } else {
                res0[(size_t)R * 64 + (c - 64)] = gelu_exact(acc[i][j] + br0[c - 64]);
            }
        }
    }
}

// ---------------- scatter: agg[dst] += h[src], 16 threads/edge ----------------
__global__ __launch_bounds__(256) void k_scatter(
    const int* __restrict__ src, const int* __restrict__ dst,
    const float* __restrict__ h, float* __restrict__ agg)
{
    long long gid = (long long)blockIdx.x * 256 + threadIdx.x;
    int e = (int)(gid >> 4);
    int q = (int)(gid & 15);
    if (e < N_EDGES) {
        int s = src[e], d = dst[e];
        float4 v = *(const float4*)(h + (size_t)s * 64 + q * 4);
        float* o = agg + (size_t)d * 64 + q * 4;
        atomicAdd(o + 0, v.x);
        atomicAdd(o + 1, v.y);
        atomicAdd(o + 2, v.z);
        atomicAdd(o + 3, v.w);
    }
}

// ---------------- layer0 epilogue: new = gelu(agg*dn_in + b0) + res0 (in-place on res0) ----------------
__global__ void k_ep0(const float* __restrict__ agg, const float* __restrict__ b0,
                      const float* __restrict__ dn_in, float* __restrict__ newbuf)
{
    int idx = blockIdx.x * 256 + threadIdx.x;
    if (idx < N_NODES * HID) {
        int r = idx >> 6, c = idx & 63;
        float v = gelu_exact(agg[idx] * dn_in[r] + b0[c]) + newbuf[idx];
        newbuf[idx] = v;
    }
}

// ---------------- BN stats: partial sums per column ----------------
__global__ __launch_bounds__(256) void k_stats_partial(const float* __restrict__ x,
        double* __restrict__ psum, double* __restrict__ psumsq)
{
    int t = threadIdx.x;
    int c = t & 63, rq = t >> 6;
    int per = (N_NODES + SB - 1) / SB;
    int r0 = blockIdx.x * per;
    int r1 = r0 + per; if (r1 > N_NODES) r1 = N_NODES;
    double s = 0.0, s2 = 0.0;
    for (int r = r0 + rq; r < r1; r += 4) {
        float v = x[(size_t)r * 64 + c];
        s += v; s2 += (double)v * v;
    }
    __shared__ double ls[4][64], ls2[4][64];
    ls[rq][c] = s; ls2[rq][c] = s2;
    __syncthreads();
    if (t < 64) {
        double a = ls[0][t] + ls[1][t] + ls[2][t] + ls[3][t];
        double a2 = ls2[0][t] + ls2[1][t] + ls2[2][t] + ls2[3][t];
        psum[blockIdx.x * 64 + t] = a;
        psumsq[blockIdx.x * 64 + t] = a2;
    }
}

__global__ void k_stats_final(const double* __restrict__ psum, const double* __restrict__ psumsq,
                              const float* __restrict__ g, const float* __restrict__ be,
                              float* __restrict__ scale, float* __restrict__ shift)
{
    int c = threadIdx.x;
    if (c < 64) {
        double s = 0.0, s2 = 0.0;
        for (int b = 0; b < SB; ++b) { s += psum[b * 64 + c]; s2 += psumsq[b * 64 + c]; }
        double mean = s / N_NODES;
        double var = s2 / N_NODES - mean * mean;
        float inv = (float)(1.0 / sqrt(var + (double)EPS)) * g[c];
        scale[c] = inv;
        shift[c] = be[c] - (float)mean * inv;
    }
}

// ---------------- normalize layer0 output, produce x1 (in-place) and h1 = x1*dn_out ----------------
__global__ void k_norm1(const float* __restrict__ scale, const float* __restrict__ shift,
                        const float* __restrict__ dn_out,
                        float* __restrict__ x1, float* __restrict__ h1)
{
    int idx = blockIdx.x * 256 + threadIdx.x;
    if (idx < N_NODES * HID) {
        int r = idx >> 6, c = idx & 63;
        float v = x1[idx] * scale[c] + shift[c];
        x1[idx] = v;
        h1[idx] = v * dn_out[r];
    }
}

// ---------------- layer1 fused GEMM: new1 = gelu(dn_in*(agg@W1)+b1) + gelu(x1@Wr1+br1) ----------------
__global__ __launch_bounds__(256) void k_gemm1(
    const float* __restrict__ agg, const float* __restrict__ x1,
    const float* __restrict__ W1, const float* __restrict__ b1_,
    const float* __restrict__ Wr1, const float* __restrict__ br1,
    const float* __restrict__ dn_in,
    float* __restrict__ out_new)
{
    __shared__ float w1s[64][64];
    __shared__ float wr1s[64][64];
    __shared__ float as[32][68];
    __shared__ float bs[32][68];
    int t = threadIdx.x;
    int row0 = blockIdx.x * 32;

    for (int i = 0; i < 16; ++i) {
        int idx = t + i * 256;
        int k = idx >> 6, c = idx & 63;
        w1s[k][c] = W1[idx];
        wr1s[k][c] = Wr1[idx];
    }
    for (int i = 0; i < 2; ++i) {
        int j = t + i * 256;
        int r = j >> 4, kq = j & 15;
        *(float4*)&as[r][kq * 4] = *(const float4*)(agg + (size_t)(row0 + r) * 64 + kq * 4);
        *(float4*)&bs[r][kq * 4] = *(const float4*)(x1 + (size_t)(row0 + r) * 64 + kq * 4);
    }
    __syncthreads();

    int tr = t >> 5, tc = t & 31;  // rows tr*4+i, cols tc*2+j
    float ap[4][2] = {}, aq[4][2] = {};
    for (int k = 0; k < 64; ++k) {
        float2 wp = *(const float2*)&w1s[k][tc * 2];
        float2 wq = *(const float2*)&wr1s[k][tc * 2];
        for (int i = 0; i < 4; ++i) {
            float a = as[tr * 4 + i][k];
            float b = bs[tr * 4 + i][k];
            ap[i][0] += a * wp.x; ap[i][1] += a * wp.y;
            aq[i][0] += b * wq.x; aq[i][1] += b * wq.y;
        }
    }

    for (int i = 0; i < 4; ++i) {
        int R = row0 + tr * 4 + i;
        float dn = dn_in[R];
        for (int j = 0; j < 2; ++j) {
            int c = tc * 2 + j;
            float vp = gelu_exact(dn * ap[i][j] + b1_[c]);
            float vq = gelu_exact(aq[i][j] + br1[c]);
            out_new[(size_t)R * 64 + c] = vp + vq;
        }
    }
}

// ---------------- head: out[g] = (new1[off[g]]*scale+shift) @ Wl + bl ----------------
__global__ void k_final(const int* __restrict__ offsets,
                        const float* __restrict__ h2,
                        const float* __restrict__ scale, const float* __restrict__ shift,
                        const float* __restrict__ Wl, const float* __restrict__ bl,
                        float* __restrict__ out)
{
    __shared__ float xv[64];
    int g = blockIdx.x;
    int t = threadIdx.x;
    int row = offsets[g];
    if (t < 64) xv[t] = h2[(size_t)row * 64 + t] * scale[t] + shift[t];
    __syncthreads();
    if (t < N_CLS) {
        float s = bl[t];
        for (int k = 0; k < 64; ++k) s += xv[k] * Wl[k * N_CLS + t];
        out[g * N_CLS + t] = s;
    }
}

extern "C" void kernel_launch(void* const* d_in, const int* in_sizes, int n_in,
                              void* d_out, int out_size, void* d_ws, size_t ws_size,
                              hipStream_t stream)
{
    const float* feats = (const float*)d_in[0];
    const int* src     = (const int*)d_in[1];
    const int* dst     = (const int*)d_in[2];
    const int* offsets = (const int*)d_in[3];
    const float* W0  = (const float*)d_in[4];
    const float* b0  = (const float*)d_in[5];
    const float* Wr0 = (const float*)d_in[6];
    const float* br0 = (const float*)d_in[7];
    const float* g0  = (const float*)d_in[8];
    const float* be0 = (const float*)d_in[9];
    const float* W1  = (const float*)d_in[10];
    const float* b1  = (const float*)d_in[11];
    const float* Wr1 = (const float*)d_in[12];
    const float* br1 = (const float*)d_in[13];
    const float* g1  = (const float*)d_in[14];
    const float* be1 = (const float*)d_in[15];
    const float* Wl  = (const float*)d_in[16];
    const float* bl  = (const float*)d_in[17];
    float* out = (float*)d_out;

    char* ws = (char*)d_ws;
    size_t off = 0;
    auto alloc = [&](size_t bytes) -> void* {
        off = (off + 255) & ~(size_t)255;
        void* p = ws + off;
        off += bytes;
        return p;
    };

    const size_t NB = (size_t)N_NODES * HID * sizeof(float);  // 25.6MB
    float* A = (float*)alloc(NB);          // h0 / h1 / new1
    float* B = (float*)alloc(NB);          // res0 / new0 / x1
    float* C = (float*)alloc(NB);          // agg
    float* dnblk = (float*)alloc(2 * (size_t)N_NODES * sizeof(float));
    float* dn_out = dnblk;
    float* dn_in  = dnblk + N_NODES;
    double* psum   = (double*)alloc((size_t)SB * 64 * sizeof(double));
    double* psumsq = (double*)alloc((size_t)SB * 64 * sizeof(double));
    float* scale0 = (float*)alloc(64 * sizeof(float));
    float* shift0 = (float*)alloc(64 * sizeof(float));
    float* scale1 = (float*)alloc(64 * sizeof(float));
    float* shift1 = (float*)alloc(64 * sizeof(float));
    (void)ws_size; (void)n_in; (void)in_sizes; (void)out_size;

    // degrees
    hipMemsetAsync(dnblk, 0, 2 * (size_t)N_NODES * sizeof(float), stream);
    k_degree<<<(N_EDGES + 255) / 256, 256, 0, stream>>>(src, dst, dn_out, dn_in);
    k_dn<<<(2 * N_NODES + 255) / 256, 256, 0, stream>>>(dnblk);

    // layer 0
    k_gemm0<<<N_NODES / 32, 256, 0, stream>>>(feats, W0, Wr0, br0, dn_out, A, B);
    hipMemsetAsync(C, 0, NB, stream);
    k_scatter<<<(N_EDGES * 16) / 256, 256, 0, stream>>>(src, dst, A, C);
    k_ep0<<<(N_NODES * HID) / 256, 256, 0, stream>>>(C, b0, dn_in, B);
    k_stats_partial<<<SB, 256, 0, stream>>>(B, psum, psumsq);
    k_stats_final<<<1, 64, 0, stream>>>(psum, psumsq, g0, be0, scale0, shift0);
    k_norm1<<<(N_NODES * HID) / 256, 256, 0, stream>>>(scale0, shift0, dn_out, B, A);

    // layer 1
    hipMemsetAsync(C, 0, NB, stream);
    k_scatter<<<(N_EDGES * 16) / 256, 256, 0, stream>>>(src, dst, A, C);
    k_gemm1<<<N_NODES / 32, 256, 0, stream>>>(C, B, W1, b1, Wr1, br1, dn_in, A);
    k_stats_partial<<<SB, 256, 0, stream>>>(A, psum, psumsq);
    k_stats_final<<<1, 64, 0, stream>>>(psum, psumsq, g1, be1, scale1, shift1);

    // head
    k_final<<<N_GRAPHS, 64, 0, stream>>>(offsets, A, scale1, shift1, Wl, bl, out);
}

// Round 3
// 580.474 us; speedup vs baseline: 3.6080x; 3.6080x over previous
//
#include <hip/hip_runtime.h>
#include <hip/hip_bf16.h>
#include <math.h>

#define N_NODES 100000
#define N_EDGES 1000000
#define N_GRAPHS 100
#define IN_F 128
#define HID 64
#define N_CLS 40
#define EPS 1e-5f
#define SB 512          // stats partial blocks
#define SCAN_BLK 391    // 391*256 = 100096 >= N_NODES+1

__device__ __forceinline__ float gelu_exact(float x) {
    return 0.5f * x * (1.0f + erff(x * 0.70710678118654752f));
}

// ---------------- degrees (int histograms) ----------------
__global__ void k_degree(const int* __restrict__ src, const int* __restrict__ dst,
                         int* __restrict__ cnt_out, int* __restrict__ cnt_in) {
    int i = blockIdx.x * blockDim.x + threadIdx.x;
    if (i < N_EDGES) {
        atomicAdd(&cnt_out[src[i]], 1);
        atomicAdd(&cnt_in[dst[i]], 1);
    }
}

__global__ void k_dn(const int* __restrict__ cnt_out, const int* __restrict__ cnt_in,
                     float* __restrict__ dn_out, float* __restrict__ dn_in) {
    int i = blockIdx.x * blockDim.x + threadIdx.x;
    if (i < N_NODES) {
        int co = cnt_out[i], ci = cnt_in[i];
        dn_out[i] = rsqrtf((float)(co > 0 ? co : 1));
        dn_in[i]  = rsqrtf((float)(ci > 0 ? ci : 1));
    }
}

// ---------------- CSR build: reduce / scan / fill ----------------
__global__ __launch_bounds__(256) void k_scan_reduce(const int* __restrict__ cnt,
                                                     int* __restrict__ bsum) {
    __shared__ int sh[256];
    int t = threadIdx.x;
    int i = blockIdx.x * 256 + t;
    int c = (i < N_NODES) ? cnt[i] : 0;
    sh[t] = c;
    __syncthreads();
    for (int d = 128; d > 0; d >>= 1) {
        if (t < d) sh[t] += sh[t + d];
        __syncthreads();
    }
    if (t == 0) bsum[blockIdx.x] = sh[0];
}

__global__ void k_scan_bsum(int* __restrict__ bsum, int* __restrict__ bpre) {
    if (threadIdx.x == 0) {
        int run = 0;
        for (int b = 0; b < SCAN_BLK; ++b) { bpre[b] = run; run += bsum[b]; }
    }
}

__global__ __launch_bounds__(256) void k_scan_write(const int* __restrict__ cnt,
                                                    const int* __restrict__ bpre,
                                                    int* __restrict__ row_start,
                                                    int* __restrict__ cursor) {
    __shared__ int sh[256];
    int t = threadIdx.x;
    int i = blockIdx.x * 256 + t;
    int c = (i < N_NODES) ? cnt[i] : 0;
    sh[t] = c;
    __syncthreads();
    // Hillis-Steele inclusive scan
    for (int d = 1; d < 256; d <<= 1) {
        int v = (t >= d) ? sh[t - d] : 0;
        __syncthreads();
        sh[t] += v;
        __syncthreads();
    }
    int excl = sh[t] - c + bpre[blockIdx.x];
    if (i <= N_NODES) {
        row_start[i] = excl;
        cursor[i] = excl;
    }
}

__global__ void k_fill(const int* __restrict__ src, const int* __restrict__ dst,
                       int* __restrict__ cursor, int* __restrict__ csr_src) {
    int e = blockIdx.x * blockDim.x + threadIdx.x;
    if (e < N_EDGES) {
        int d = dst[e];
        int pos = atomicAdd(&cursor[d], 1);
        csr_src[pos] = src[e];
    }
}

// ---------------- layer0 fused GEMM: h0 = dn_out*(x@W0), res0 = gelu(x@Wr0+br0) ----------------
__global__ __launch_bounds__(256) void k_gemm0(
    const float* __restrict__ x, const float* __restrict__ W0,
    const float* __restrict__ Wr0, const float* __restrict__ br0,
    const float* __restrict__ dn_out,
    float* __restrict__ h0, float* __restrict__ res0)
{
    __shared__ float ws[64][128];   // half-K of [W0|Wr0], 32KB
    __shared__ float xs[32][132];   // 32 rows of x, padded
    int t = threadIdx.x;
    int row0 = blockIdx.x * 32;

    for (int i = 0; i < 4; ++i) {
        int j = t + i * 256;
        int r = j >> 5, kq = j & 31;
        float4 v = *(const float4*)(x + (size_t)(row0 + r) * IN_F + kq * 4);
        *(float4*)(&xs[r][kq * 4]) = v;
    }

    int tr = t >> 5, tc = t & 31;
    float acc[4][4] = {};

    for (int kh = 0; kh < 2; ++kh) {
        __syncthreads();
        for (int i = 0; i < 32; ++i) {
            int idx = t + i * 256;
            int k = idx >> 7, c = idx & 127;
            int kg = kh * 64 + k;
            ws[k][c] = (c < 64) ? W0[kg * 64 + c] : Wr0[kg * 64 + (c - 64)];
        }
        __syncthreads();
        for (int k = 0; k < 64; ++k) {
            float4 w = *(const float4*)(&ws[k][tc * 4]);
            int kk = kh * 64 + k;
            float a0 = xs[tr * 4 + 0][kk];
            float a1 = xs[tr * 4 + 1][kk];
            float a2 = xs[tr * 4 + 2][kk];
            float a3 = xs[tr * 4 + 3][kk];
            acc[0][0] += a0 * w.x; acc[0][1] += a0 * w.y; acc[0][2] += a0 * w.z; acc[0][3] += a0 * w.w;
            acc[1][0] += a1 * w.x; acc[1][1] += a1 * w.y; acc[1][2] += a1 * w.z; acc[1][3] += a1 * w.w;
            acc[2][0] += a2 * w.x; acc[2][1] += a2 * w.y; acc[2][2] += a2 * w.z; acc[2][3] += a2 * w.w;
            acc[3][0] += a3 * w.x; acc[3][1] += a3 * w.y; acc[3][2] += a3 * w.z; acc[3][3] += a3 * w.w;
        }
    }

    int cbase = tc * 4;
    for (int i = 0; i < 4; ++i) {
        int R = row0 + tr * 4 + i;
        float dn = dn_out[R];
        for (int j = 0; j < 4; ++j) {
            int c = cbase + j;
            if (c < 64) {
                h0[(size_t)R * 64 + c] = dn * acc[i][j];
            } else {
                res0[(size_t)R * 64 + (c - 64)] = gelu_exact(acc[i][j] + br0[c - 64]);
            }
        }
    }
}

// ---------------- gather-aggregate, one wave per node ----------------
// mode 0: out[n] = gelu(acc*dn_in + b0) + out[n]   (layer0: residual in-place)
// mode 1: out[n] = acc*dn_in                        (layer1: pre-scaled agg)
template <int MODE>
__global__ __launch_bounds__(256) void k_agg(
    const int* __restrict__ row_start, const int* __restrict__ csr_src,
    const float* __restrict__ h, const float* __restrict__ dn_in,
    const float* __restrict__ b0, float* __restrict__ out)
{
    int node = blockIdx.x * 4 + (threadIdx.x >> 6);
    int lane = threadIdx.x & 63;
    if (node >= N_NODES) return;
    int beg = row_start[node], end = row_start[node + 1];
    float acc = 0.0f;
    for (int j = beg; j < end; j += 64) {
        int eid = (j + lane < end) ? csr_src[j + lane] : 0;
        int cnt = end - j; if (cnt > 64) cnt = 64;
        for (int u = 0; u < cnt; ++u) {
            int s = __shfl(eid, u);
            acc += h[(size_t)s * 64 + lane];
        }
    }
    size_t o = (size_t)node * 64 + lane;
    if (MODE == 0) {
        out[o] = gelu_exact(acc * dn_in[node] + b0[lane]) + out[o];
    } else {
        out[o] = acc * dn_in[node];
    }
}

// ---------------- BN stats ----------------
__global__ __launch_bounds__(256) void k_stats_partial(const float* __restrict__ x,
        double* __restrict__ psum, double* __restrict__ psumsq)
{
    int t = threadIdx.x;
    int c = t & 63, rq = t >> 6;
    int per = (N_NODES + SB - 1) / SB;
    int r0 = blockIdx.x * per;
    int r1 = r0 + per; if (r1 > N_NODES) r1 = N_NODES;
    double s = 0.0, s2 = 0.0;
    for (int r = r0 + rq; r < r1; r += 4) {
        float v = x[(size_t)r * 64 + c];
        s += v; s2 += (double)v * v;
    }
    __shared__ double ls[4][64], ls2[4][64];
    ls[rq][c] = s; ls2[rq][c] = s2;
    __syncthreads();
    if (t < 64) {
        double a = ls[0][t] + ls[1][t] + ls[2][t] + ls[3][t];
        double a2 = ls2[0][t] + ls2[1][t] + ls2[2][t] + ls2[3][t];
        psum[blockIdx.x * 64 + t] = a;
        psumsq[blockIdx.x * 64 + t] = a2;
    }
}

__global__ void k_stats_final(const double* __restrict__ psum, const double* __restrict__ psumsq,
                              const float* __restrict__ g, const float* __restrict__ be,
                              float* __restrict__ scale, float* __restrict__ shift)
{
    int c = threadIdx.x;
    if (c < 64) {
        double s = 0.0, s2 = 0.0;
        for (int b = 0; b < SB; ++b) { s += psum[b * 64 + c]; s2 += psumsq[b * 64 + c]; }
        double mean = s / N_NODES;
        double var = s2 / N_NODES - mean * mean;
        float inv = (float)(1.0 / sqrt(var + (double)EPS)) * g[c];
        scale[c] = inv;
        shift[c] = be[c] - (float)mean * inv;
    }
}

// ---------------- normalize layer0 output -> x1 (in-place), h1 = x1*dn_out ----------------
__global__ void k_norm1(const float* __restrict__ scale, const float* __restrict__ shift,
                        const float* __restrict__ dn_out,
                        float* __restrict__ x1, float* __restrict__ h1)
{
    int idx = blockIdx.x * 256 + threadIdx.x;
    if (idx < N_NODES * HID) {
        int r = idx >> 6, c = idx & 63;
        float v = x1[idx] * scale[c] + shift[c];
        x1[idx] = v;
        h1[idx] = v * dn_out[r];
    }
}

// ---------------- layer1 fused GEMM: new1 = gelu(aggs@W1+b1) + gelu(x1@Wr1+br1) ----------------
__global__ __launch_bounds__(256) void k_gemm1(
    const float* __restrict__ aggs, const float* __restrict__ x1,
    const float* __restrict__ W1, const float* __restrict__ b1_,
    const float* __restrict__ Wr1, const float* __restrict__ br1,
    float* __restrict__ out_new)
{
    __shared__ float w1s[64][64];
    __shared__ float wr1s[64][64];
    __shared__ float as[32][68];
    __shared__ float bs[32][68];
    int t = threadIdx.x;
    int row0 = blockIdx.x * 32;

    for (int i = 0; i < 16; ++i) {
        int idx = t + i * 256;
        int k = idx >> 6, c = idx & 63;
        w1s[k][c] = W1[idx];
        wr1s[k][c] = Wr1[idx];
    }
    for (int i = 0; i < 2; ++i) {
        int j = t + i * 256;
        int r = j >> 4, kq = j & 15;
        *(float4*)&as[r][kq * 4] = *(const float4*)(aggs + (size_t)(row0 + r) * 64 + kq * 4);
        *(float4*)&bs[r][kq * 4] = *(const float4*)(x1 + (size_t)(row0 + r) * 64 + kq * 4);
    }
    __syncthreads();

    int tr = t >> 5, tc = t & 31;
    float ap[4][2] = {}, aq[4][2] = {};
    for (int k = 0; k < 64; ++k) {
        float2 wp = *(const float2*)&w1s[k][tc * 2];
        float2 wq = *(const float2*)&wr1s[k][tc * 2];
        for (int i = 0; i < 4; ++i) {
            float a = as[tr * 4 + i][k];
            float b = bs[tr * 4 + i][k];
            ap[i][0] += a * wp.x; ap[i][1] += a * wp.y;
            aq[i][0] += b * wq.x; aq[i][1] += b * wq.y;
        }
    }

    for (int i = 0; i < 4; ++i) {
        int R = row0 + tr * 4 + i;
        for (int j = 0; j < 2; ++j) {
            int c = tc * 2 + j;
            float vp = gelu_exact(ap[i][j] + b1_[c]);
            float vq = gelu_exact(aq[i][j] + br1[c]);
            out_new[(size_t)R * 64 + c] = vp + vq;
        }
    }
}

// ---------------- head ----------------
__global__ void k_final(const int* __restrict__ offsets,
                        const float* __restrict__ h2,
                        const float* __restrict__ scale, const float* __restrict__ shift,
                        const float* __restrict__ Wl, const float* __restrict__ bl,
                        float* __restrict__ out)
{
    __shared__ float xv[64];
    int g = blockIdx.x;
    int t = threadIdx.x;
    int row = offsets[g];
    if (t < 64) xv[t] = h2[(size_t)row * 64 + t] * scale[t] + shift[t];
    __syncthreads();
    if (t < N_CLS) {
        float s = bl[t];
        for (int k = 0; k < 64; ++k) s += xv[k] * Wl[k * N_CLS + t];
        out[g * N_CLS + t] = s;
    }
}

extern "C" void kernel_launch(void* const* d_in, const int* in_sizes, int n_in,
                              void* d_out, int out_size, void* d_ws, size_t ws_size,
                              hipStream_t stream)
{
    const float* feats = (const float*)d_in[0];
    const int* src     = (const int*)d_in[1];
    const int* dst     = (const int*)d_in[2];
    const int* offsets = (const int*)d_in[3];
    const float* W0  = (const float*)d_in[4];
    const float* b0  = (const float*)d_in[5];
    const float* Wr0 = (const float*)d_in[6];
    const float* br0 = (const float*)d_in[7];
    const float* g0  = (const float*)d_in[8];
    const float* be0 = (const float*)d_in[9];
    const float* W1  = (const float*)d_in[10];
    const float* b1  = (const float*)d_in[11];
    const float* Wr1 = (const float*)d_in[12];
    const float* br1 = (const float*)d_in[13];
    const float* g1  = (const float*)d_in[14];
    const float* be1 = (const float*)d_in[15];
    const float* Wl  = (const float*)d_in[16];
    const float* bl  = (const float*)d_in[17];
    float* out = (float*)d_out;

    char* ws = (char*)d_ws;
    size_t off = 0;
    auto alloc = [&](size_t bytes) -> void* {
        off = (off + 255) & ~(size_t)255;
        void* p = ws + off;
        off += bytes;
        return p;
    };

    const size_t NB = (size_t)N_NODES * HID * sizeof(float);  // 25.6MB
    float* A = (float*)alloc(NB);          // h0 / h1 / new1
    float* B = (float*)alloc(NB);          // res0 / new0 / x1
    float* C = (float*)alloc(NB);          // aggs (layer1)
    int* cnts = (int*)alloc(2 * (size_t)N_NODES * sizeof(int));  // ONE block: cnt_out | cnt_in
    int* cnt_out = cnts;
    int* cnt_in  = cnts + N_NODES;
    float* dn_out = (float*)alloc(N_NODES * sizeof(float));
    float* dn_in  = (float*)alloc(N_NODES * sizeof(float));
    int* bsum = (int*)alloc(SCAN_BLK * sizeof(int));
    int* bpre = (int*)alloc(SCAN_BLK * sizeof(int));
    int* row_start = (int*)alloc((SCAN_BLK * 256 + 1) * sizeof(int));
    int* cursor    = (int*)alloc((SCAN_BLK * 256 + 1) * sizeof(int));
    int* csr_src   = (int*)alloc((size_t)N_EDGES * sizeof(int));
    double* psum   = (double*)alloc((size_t)SB * 64 * sizeof(double));
    double* psumsq = (double*)alloc((size_t)SB * 64 * sizeof(double));
    float* scale0 = (float*)alloc(64 * sizeof(float));
    float* shift0 = (float*)alloc(64 * sizeof(float));
    float* scale1 = (float*)alloc(64 * sizeof(float));
    float* shift1 = (float*)alloc(64 * sizeof(float));
    (void)ws_size; (void)n_in; (void)in_sizes; (void)out_size;

    // degrees + CSR build (once, reused by both layers)
    hipMemsetAsync(cnts, 0, 2 * (size_t)N_NODES * sizeof(int), stream);
    k_degree<<<(N_EDGES + 255) / 256, 256, 0, stream>>>(src, dst, cnt_out, cnt_in);
    k_dn<<<(N_NODES + 255) / 256, 256, 0, stream>>>(cnt_out, cnt_in, dn_out, dn_in);
    k_scan_reduce<<<SCAN_BLK, 256, 0, stream>>>(cnt_in, bsum);
    k_scan_bsum<<<1, 64, 0, stream>>>(bsum, bpre);
    k_scan_write<<<SCAN_BLK, 256, 0, stream>>>(cnt_in, bpre, row_start, cursor);
    k_fill<<<(N_EDGES + 255) / 256, 256, 0, stream>>>(src, dst, cursor, csr_src);

    // layer 0
    k_gemm0<<<N_NODES / 32, 256, 0, stream>>>(feats, W0, Wr0, br0, dn_out, A, B);
    k_agg<0><<<N_NODES / 4, 256, 0, stream>>>(row_start, csr_src, A, dn_in, b0, B);
    k_stats_partial<<<SB, 256, 0, stream>>>(B, psum, psumsq);
    k_stats_final<<<1, 64, 0, stream>>>(psum, psumsq, g0, be0, scale0, shift0);
    k_norm1<<<(N_NODES * HID) / 256, 256, 0, stream>>>(scale0, shift0, dn_out, B, A);

    // layer 1
    k_agg<1><<<N_NODES / 4, 256, 0, stream>>>(row_start, csr_src, A, dn_in, nullptr, C);
    k_gemm1<<<N_NODES / 32, 256, 0, stream>>>(C, B, W1, b1, Wr1, br1, A);
    k_stats_partial<<<SB, 256, 0, stream>>>(A, psum, psumsq);
    k_stats_final<<<1, 64, 0, stream>>>(psum, psumsq, g1, be1, scale1, shift1);

    // head
    k_final<<<N_GRAPHS, 64, 0, stream>>>(offsets, A, scale1, shift1, Wl, bl, out);
}

// Round 4
// 431.803 us; speedup vs baseline: 4.8502x; 1.3443x over previous
//
#include <hip/hip_runtime.h>
#include <hip/hip_bf16.h>
#include <math.h>

#define N_NODES 100000
#define N_EDGES 1000000
#define N_GRAPHS 100
#define IN_F 128
#define HID 64
#define N_CLS 40
#define EPS 1e-5f
#define SB 512          // stats partial blocks
#define SCAN_BLK 391    // 391*256 = 100096 >= N_NODES+1
#define NTILE 1563      // ceil(N_NODES/64)

typedef __attribute__((ext_vector_type(8))) short bf16x8;
typedef __attribute__((ext_vector_type(4))) float f32x4;

__device__ __forceinline__ float gelu_exact(float x) {
    return 0.5f * x * (1.0f + erff(x * 0.70710678118654752f));
}

__device__ __forceinline__ unsigned short f2b(float f) {  // f32 -> bf16 RNE
    unsigned u = __builtin_bit_cast(unsigned, f);
    return (unsigned short)((u + 0x7FFFu + ((u >> 16) & 1u)) >> 16);
}
__device__ __forceinline__ float b2f(unsigned short h) {
    unsigned u = ((unsigned)h) << 16;
    return __builtin_bit_cast(float, u);
}

// ---------------- weight prep: Wt0[n][k] bf16 (n<64:W0, else Wr0), Wt1[n][k] (n<64:W1, else Wr1)
__global__ void k_prep_w(const float* __restrict__ W0, const float* __restrict__ Wr0,
                         const float* __restrict__ W1, const float* __restrict__ Wr1,
                         unsigned short* __restrict__ Wt0, unsigned short* __restrict__ Wt1) {
    int t = blockIdx.x * 256 + threadIdx.x;
    for (int idx = t; idx < 128 * 128; idx += gridDim.x * 256) {
        int n = idx >> 7, k = idx & 127;
        float v = (n < 64) ? W0[k * 64 + n] : Wr0[k * 64 + (n - 64)];
        Wt0[n * 128 + k] = f2b(v);
    }
    for (int idx = t; idx < 128 * 64; idx += gridDim.x * 256) {
        int n = idx >> 6, k = idx & 63;
        float v = (n < 64) ? W1[k * 64 + n] : Wr1[k * 64 + (n - 64)];
        Wt1[n * 64 + k] = f2b(v);
    }
}

// ---------------- degrees ----------------
__global__ void k_degree(const int* __restrict__ src, const int* __restrict__ dst,
                         int* __restrict__ cnt_out, int* __restrict__ cnt_in) {
    int i = blockIdx.x * blockDim.x + threadIdx.x;
    if (i < N_EDGES) {
        atomicAdd(&cnt_out[src[i]], 1);
        atomicAdd(&cnt_in[dst[i]], 1);
    }
}

// ---------------- CSR build ----------------
__global__ __launch_bounds__(256) void k_scan_reduce(const int* __restrict__ cnt,
                                                     int* __restrict__ bsum) {
    __shared__ int sh[256];
    int t = threadIdx.x;
    int i = blockIdx.x * 256 + t;
    int c = (i < N_NODES) ? cnt[i] : 0;
    sh[t] = c;
    __syncthreads();
    for (int d = 128; d > 0; d >>= 1) {
        if (t < d) sh[t] += sh[t + d];
        __syncthreads();
    }
    if (t == 0) bsum[blockIdx.x] = sh[0];
}

__global__ __launch_bounds__(512) void k_scan_bsum(const int* __restrict__ bsum,
                                                   int* __restrict__ bpre) {
    __shared__ int sh[512];
    int t = threadIdx.x;
    int v = (t < SCAN_BLK) ? bsum[t] : 0;
    sh[t] = v;
    __syncthreads();
    for (int d = 1; d < 512; d <<= 1) {
        int x = (t >= d) ? sh[t - d] : 0;
        __syncthreads();
        sh[t] += x;
        __syncthreads();
    }
    if (t < SCAN_BLK) bpre[t] = sh[t] - v;
}

__global__ __launch_bounds__(256) void k_scan_write(const int* __restrict__ cnt_in,
                                                    const int* __restrict__ cnt_out,
                                                    const int* __restrict__ bpre,
                                                    int* __restrict__ row_start,
                                                    int* __restrict__ cursor,
                                                    float* __restrict__ dn_out,
                                                    float* __restrict__ dn_in) {
    __shared__ int sh[256];
    int t = threadIdx.x;
    int i = blockIdx.x * 256 + t;
    int c = (i < N_NODES) ? cnt_in[i] : 0;
    sh[t] = c;
    __syncthreads();
    for (int d = 1; d < 256; d <<= 1) {
        int v = (t >= d) ? sh[t - d] : 0;
        __syncthreads();
        sh[t] += v;
        __syncthreads();
    }
    int excl = sh[t] - c + bpre[blockIdx.x];
    if (i <= N_NODES) {
        row_start[i] = excl;
        cursor[i] = excl;
    }
    if (i < N_NODES) {
        int co = cnt_out[i];
        dn_out[i] = rsqrtf((float)(co > 0 ? co : 1));
        dn_in[i]  = rsqrtf((float)(c > 0 ? c : 1));
    }
}

__global__ void k_fill(const int* __restrict__ src, const int* __restrict__ dst,
                       int* __restrict__ cursor, int* __restrict__ csr_src) {
    int e = blockIdx.x * blockDim.x + threadIdx.x;
    if (e < N_EDGES) {
        int d = dst[e];
        int pos = atomicAdd(&cursor[d], 1);
        csr_src[pos] = src[e];
    }
}

// ---------------- layer0 MFMA GEMM: h0b = bf16(dn_out*(x@W0)), res0 = gelu(x@Wr0+br0)
// block: 64 rows x 128 cols, 4 waves (16 rows each, all 128 cols); B-frags in VGPRs.
__global__ __launch_bounds__(256) void k_gemm0(
    const float* __restrict__ x, const unsigned short* __restrict__ Wt0,
    const float* __restrict__ br0, const float* __restrict__ dn_out,
    unsigned short* __restrict__ h0b, float* __restrict__ res0)
{
    __shared__ unsigned short xs[64][136];   // padded: stride 272B = 17 x 16B
    int t = threadIdx.x;
    int lane = t & 63;
    int w = t >> 6;
    int g = lane >> 4, r16 = lane & 15;

    // B fragments: 8 col-tiles x 4 k-steps, loaded once per block
    bf16x8 bfrag[8][4];
    for (int ct = 0; ct < 8; ++ct) {
        int n = ct * 16 + r16;
        for (int ks = 0; ks < 4; ++ks)
            bfrag[ct][ks] = *(const bf16x8*)(Wt0 + n * 128 + ks * 32 + g * 8);
    }
    float br_c[8];
    for (int ct = 4; ct < 8; ++ct) br_c[ct] = br0[(ct - 4) * 16 + r16];

    for (int tile = blockIdx.x; tile < NTILE; tile += gridDim.x) {
        int row0 = tile * 64;
        // stage 64 rows of x -> bf16 LDS
        {
            int rr = t >> 2, q = t & 3;
            int R = row0 + rr;
            bool ok = (R < N_NODES);
            const float* xp = x + (size_t)R * IN_F + q * 32;
            for (int i = 0; i < 8; ++i) {
                float4 v = ok ? *(const float4*)(xp + i * 4) : make_float4(0.f, 0.f, 0.f, 0.f);
                unsigned p0 = (unsigned)f2b(v.x) | ((unsigned)f2b(v.y) << 16);
                unsigned p1 = (unsigned)f2b(v.z) | ((unsigned)f2b(v.w) << 16);
                *(uint2*)(&xs[rr][q * 32 + i * 4]) = make_uint2(p0, p1);
            }
        }
        __syncthreads();

        int arow = w * 16 + r16;
        bf16x8 a[4];
        for (int ks = 0; ks < 4; ++ks)
            a[ks] = *(const bf16x8*)(&xs[arow][ks * 32 + g * 8]);

        f32x4 acc[8];
        for (int ct = 0; ct < 8; ++ct) acc[ct] = (f32x4){0.f, 0.f, 0.f, 0.f};
        for (int ks = 0; ks < 4; ++ks)
            for (int ct = 0; ct < 8; ++ct)
                acc[ct] = __builtin_amdgcn_mfma_f32_16x16x32_bf16(a[ks], bfrag[ct][ks], acc[ct], 0, 0, 0);

        // epilogue: D layout col = lane&15, row = (lane>>4)*4 + reg
        int Rbase = row0 + w * 16 + g * 4;
        float dn[4];
        for (int rg = 0; rg < 4; ++rg) {
            int R = Rbase + rg;
            dn[rg] = (R < N_NODES) ? dn_out[R] : 0.f;
        }
        for (int ct = 0; ct < 8; ++ct) {
            int c = ct * 16 + r16;
            for (int rg = 0; rg < 4; ++rg) {
                int R = Rbase + rg;
                if (R < N_NODES) {
                    if (c < 64) h0b[(size_t)R * 64 + c] = f2b(dn[rg] * acc[ct][rg]);
                    else        res0[(size_t)R * 64 + (c - 64)] = gelu_exact(acc[ct][rg] + br_c[ct]);
                }
            }
        }
        __syncthreads();
    }
}

// ---------------- gather-aggregate over bf16 rows, 4 edges per wave-step ----------------
// MODE 0: out[n][c] = gelu(acc*dn_in + b0[c]) + out[n][c]   (res0 in out, in-place)
// MODE 1: out[n][c] = acc*dn_in
template <int MODE>
__global__ __launch_bounds__(256) void k_agg(
    const int* __restrict__ row_start, const int* __restrict__ csr_src,
    const unsigned short* __restrict__ hb, const float* __restrict__ dn_in,
    const float* __restrict__ b0, float* __restrict__ out)
{
    int node = blockIdx.x * 4 + (threadIdx.x >> 6);
    int lane = threadIdx.x & 63;
    int sub = lane >> 4, q = lane & 15;
    int beg = row_start[node], end = row_start[node + 1];
    float a0 = 0.f, a1 = 0.f, a2 = 0.f, a3 = 0.f;
    for (int j = beg; j < end; j += 64) {
        int idx = j + lane;
        int eid = (idx < end) ? csr_src[idx] : 0;
        int cnt = end - j; if (cnt > 64) cnt = 64;
        for (int u = sub; u < cnt; u += 4) {
            int s = __shfl(eid, u);
            uint2 v = *(const uint2*)(hb + (size_t)s * 64 + q * 4);
            a0 += b2f((unsigned short)(v.x & 0xFFFFu));
            a1 += b2f((unsigned short)(v.x >> 16));
            a2 += b2f((unsigned short)(v.y & 0xFFFFu));
            a3 += b2f((unsigned short)(v.y >> 16));
        }
    }
    a0 += __shfl_xor(a0, 16); a0 += __shfl_xor(a0, 32);
    a1 += __shfl_xor(a1, 16); a1 += __shfl_xor(a1, 32);
    a2 += __shfl_xor(a2, 16); a2 += __shfl_xor(a2, 32);
    a3 += __shfl_xor(a3, 16); a3 += __shfl_xor(a3, 32);
    if (sub == 0) {
        float dn = dn_in[node];
        size_t o = (size_t)node * 64 + q * 4;
        if (MODE == 0) {
            float4 r = *(const float4*)(out + o);
            float4 wv;
            wv.x = gelu_exact(a0 * dn + b0[q * 4 + 0]) + r.x;
            wv.y = gelu_exact(a1 * dn + b0[q * 4 + 1]) + r.y;
            wv.z = gelu_exact(a2 * dn + b0[q * 4 + 2]) + r.z;
            wv.w = gelu_exact(a3 * dn + b0[q * 4 + 3]) + r.w;
            *(float4*)(out + o) = wv;
        } else {
            float4 wv = make_float4(a0 * dn, a1 * dn, a2 * dn, a3 * dn);
            *(float4*)(out + o) = wv;
        }
    }
}

// ---------------- BN stats ----------------
__global__ __launch_bounds__(256) void k_stats_partial(const float* __restrict__ x,
        double* __restrict__ psum, double* __restrict__ psumsq)
{
    int t = threadIdx.x;
    int c = t & 63, rq = t >> 6;
    int per = (N_NODES + SB - 1) / SB;
    int r0 = blockIdx.x * per;
    int r1 = r0 + per; if (r1 > N_NODES) r1 = N_NODES;
    double s = 0.0, s2 = 0.0;
    for (int r = r0 + rq; r < r1; r += 4) {
        float v = x[(size_t)r * 64 + c];
        s += v; s2 += (double)v * v;
    }
    __shared__ double ls[4][64], ls2[4][64];
    ls[rq][c] = s; ls2[rq][c] = s2;
    __syncthreads();
    if (t < 64) {
        double a = ls[0][t] + ls[1][t] + ls[2][t] + ls[3][t];
        double a2 = ls2[0][t] + ls2[1][t] + ls2[2][t] + ls2[3][t];
        psum[blockIdx.x * 64 + t] = a;
        psumsq[blockIdx.x * 64 + t] = a2;
    }
}

__global__ void k_stats_final(const double* __restrict__ psum, const double* __restrict__ psumsq,
                              const float* __restrict__ g, const float* __restrict__ be,
                              float* __restrict__ scale, float* __restrict__ shift)
{
    int c = threadIdx.x;
    if (c < 64) {
        double s = 0.0, s2 = 0.0;
        for (int b = 0; b < SB; ++b) { s += psum[b * 64 + c]; s2 += psumsq[b * 64 + c]; }
        double mean = s / N_NODES;
        double var = s2 / N_NODES - mean * mean;
        float inv = (float)(1.0 / sqrt(var + (double)EPS)) * g[c];
        scale[c] = inv;
        shift[c] = be[c] - (float)mean * inv;
    }
}

// ---------------- normalize: x1 (f32, in-place) and h1b = bf16(x1*dn_out) ----------------
__global__ void k_norm1(const float* __restrict__ scale, const float* __restrict__ shift,
                        const float* __restrict__ dn_out,
                        float* __restrict__ x1, unsigned short* __restrict__ h1b)
{
    int idx = blockIdx.x * 256 + threadIdx.x;
    if (idx < N_NODES * HID) {
        int r = idx >> 6, c = idx & 63;
        float v = x1[idx] * scale[c] + shift[c];
        x1[idx] = v;
        h1b[idx] = f2b(v * dn_out[r]);
    }
}

// ---------------- layer1 MFMA GEMM: new1 = gelu(aggs@W1+b1) + gelu(x1@Wr1+br1), in-place on aggs
__global__ __launch_bounds__(256) void k_gemm1(
    const float* __restrict__ aggs, const float* __restrict__ x1,
    const unsigned short* __restrict__ Wt1,
    const float* __restrict__ b1_, const float* __restrict__ br1,
    float* __restrict__ out_new)
{
    __shared__ unsigned short xa[64][72];   // stride 144B = 9 x 16B
    __shared__ unsigned short xb[64][72];
    int t = threadIdx.x;
    int lane = t & 63;
    int w = t >> 6;
    int g = lane >> 4, r16 = lane & 15;

    bf16x8 bW[4][2], bR[4][2];
    for (int ct = 0; ct < 4; ++ct) {
        int n = ct * 16 + r16;
        for (int ks = 0; ks < 2; ++ks) {
            bW[ct][ks] = *(const bf16x8*)(Wt1 + n * 64 + ks * 32 + g * 8);
            bR[ct][ks] = *(const bf16x8*)(Wt1 + (64 + n) * 64 + ks * 32 + g * 8);
        }
    }
    float bias1[4], biasr[4];
    for (int ct = 0; ct < 4; ++ct) {
        bias1[ct] = b1_[ct * 16 + r16];
        biasr[ct] = br1[ct * 16 + r16];
    }

    for (int tile = blockIdx.x; tile < NTILE; tile += gridDim.x) {
        int row0 = tile * 64;
        {
            int rr = t >> 2, q = t & 3;
            int R = row0 + rr;
            bool ok = (R < N_NODES);
            const float* pa = aggs + (size_t)R * 64 + q * 16;
            const float* pb = x1 + (size_t)R * 64 + q * 16;
            for (int i = 0; i < 4; ++i) {
                float4 va = ok ? *(const float4*)(pa + i * 4) : make_float4(0.f, 0.f, 0.f, 0.f);
                float4 vb = ok ? *(const float4*)(pb + i * 4) : make_float4(0.f, 0.f, 0.f, 0.f);
                unsigned pa0 = (unsigned)f2b(va.x) | ((unsigned)f2b(va.y) << 16);
                unsigned pa1 = (unsigned)f2b(va.z) | ((unsigned)f2b(va.w) << 16);
                unsigned pb0 = (unsigned)f2b(vb.x) | ((unsigned)f2b(vb.y) << 16);
                unsigned pb1 = (unsigned)f2b(vb.z) | ((unsigned)f2b(vb.w) << 16);
                *(uint2*)(&xa[rr][q * 16 + i * 4]) = make_uint2(pa0, pa1);
                *(uint2*)(&xb[rr][q * 16 + i * 4]) = make_uint2(pb0, pb1);
            }
        }
        __syncthreads();

        int arow = w * 16 + r16;
        bf16x8 aA[2], aB[2];
        for (int ks = 0; ks < 2; ++ks) {
            aA[ks] = *(const bf16x8*)(&xa[arow][ks * 32 + g * 8]);
            aB[ks] = *(const bf16x8*)(&xb[arow][ks * 32 + g * 8]);
        }
        f32x4 accW[4], accR[4];
        for (int ct = 0; ct < 4; ++ct) {
            accW[ct] = (f32x4){0.f, 0.f, 0.f, 0.f};
            accR[ct] = (f32x4){0.f, 0.f, 0.f, 0.f};
        }
        for (int ks = 0; ks < 2; ++ks)
            for (int ct = 0; ct < 4; ++ct) {
                accW[ct] = __builtin_amdgcn_mfma_f32_16x16x32_bf16(aA[ks], bW[ct][ks], accW[ct], 0, 0, 0);
                accR[ct] = __builtin_amdgcn_mfma_f32_16x16x32_bf16(aB[ks], bR[ct][ks], accR[ct], 0, 0, 0);
            }

        int Rbase = row0 + w * 16 + g * 4;
        for (int ct = 0; ct < 4; ++ct) {
            int c = ct * 16 + r16;
            for (int rg = 0; rg < 4; ++rg) {
                int R = Rbase + rg;
                if (R < N_NODES)
                    out_new[(size_t)R * 64 + c] =
                        gelu_exact(accW[ct][rg] + bias1[ct]) + gelu_exact(accR[ct][rg] + biasr[ct]);
            }
        }
        __syncthreads();
    }
}

// ---------------- head ----------------
__global__ void k_final(const int* __restrict__ offsets,
                        const float* __restrict__ h2,
                        const float* __restrict__ scale, const float* __restrict__ shift,
                        const float* __restrict__ Wl, const float* __restrict__ bl,
                        float* __restrict__ out)
{
    __shared__ float xv[64];
    int g = blockIdx.x;
    int t = threadIdx.x;
    int row = offsets[g];
    if (t < 64) xv[t] = h2[(size_t)row * 64 + t] * scale[t] + shift[t];
    __syncthreads();
    if (t < N_CLS) {
        float s = bl[t];
        for (int k = 0; k < 64; ++k) s += xv[k] * Wl[k * N_CLS + t];
        out[g * N_CLS + t] = s;
    }
}

extern "C" void kernel_launch(void* const* d_in, const int* in_sizes, int n_in,
                              void* d_out, int out_size, void* d_ws, size_t ws_size,
                              hipStream_t stream)
{
    const float* feats = (const float*)d_in[0];
    const int* src     = (const int*)d_in[1];
    const int* dst     = (const int*)d_in[2];
    const int* offsets = (const int*)d_in[3];
    const float* W0  = (const float*)d_in[4];
    const float* b0  = (const float*)d_in[5];
    const float* Wr0 = (const float*)d_in[6];
    const float* br0 = (const float*)d_in[7];
    const float* g0  = (const float*)d_in[8];
    const float* be0 = (const float*)d_in[9];
    const float* W1  = (const float*)d_in[10];
    const float* b1  = (const float*)d_in[11];
    const float* Wr1 = (const float*)d_in[12];
    const float* br1 = (const float*)d_in[13];
    const float* g1  = (const float*)d_in[14];
    const float* be1 = (const float*)d_in[15];
    const float* Wl  = (const float*)d_in[16];
    const float* bl  = (const float*)d_in[17];
    float* out = (float*)d_out;

    char* ws = (char*)d_ws;
    size_t off = 0;
    auto alloc = [&](size_t bytes) -> void* {
        off = (off + 255) & ~(size_t)255;
        void* p = ws + off;
        off += bytes;
        return p;
    };

    const size_t NB = (size_t)N_NODES * HID * sizeof(float);  // 25.6MB
    unsigned short* Hb = (unsigned short*)alloc(NB / 2);  // h0b / h1b (bf16)
    float* B = (float*)alloc(NB);                         // res0 -> new0 -> x1
    float* C = (float*)alloc(NB);                         // aggs -> new1 (in-place per-row)
    unsigned short* Wt0 = (unsigned short*)alloc(128 * 128 * sizeof(unsigned short));
    unsigned short* Wt1 = (unsigned short*)alloc(128 * 64 * sizeof(unsigned short));
    int* cnts = (int*)alloc(2 * (size_t)N_NODES * sizeof(int));
    int* cnt_out = cnts;
    int* cnt_in  = cnts + N_NODES;
    float* dn_out = (float*)alloc(N_NODES * sizeof(float));
    float* dn_in  = (float*)alloc(N_NODES * sizeof(float));
    int* bsum = (int*)alloc(SCAN_BLK * sizeof(int));
    int* bpre = (int*)alloc(SCAN_BLK * sizeof(int));
    int* row_start = (int*)alloc((SCAN_BLK * 256 + 1) * sizeof(int));
    int* cursor    = (int*)alloc((SCAN_BLK * 256 + 1) * sizeof(int));
    int* csr_src   = (int*)alloc((size_t)N_EDGES * sizeof(int));
    double* psum   = (double*)alloc((size_t)SB * 64 * sizeof(double));
    double* psumsq = (double*)alloc((size_t)SB * 64 * sizeof(double));
    float* scale0 = (float*)alloc(64 * sizeof(float));
    float* shift0 = (float*)alloc(64 * sizeof(float));
    float* scale1 = (float*)alloc(64 * sizeof(float));
    float* shift1 = (float*)alloc(64 * sizeof(float));
    (void)ws_size; (void)n_in; (void)in_sizes; (void)out_size;

    // weight prep + degrees + CSR (reused by both layers)
    hipMemsetAsync(cnts, 0, 2 * (size_t)N_NODES * sizeof(int), stream);
    k_prep_w<<<64, 256, 0, stream>>>(W0, Wr0, W1, Wr1, Wt0, Wt1);
    k_degree<<<(N_EDGES + 255) / 256, 256, 0, stream>>>(src, dst, cnt_out, cnt_in);
    k_scan_reduce<<<SCAN_BLK, 256, 0, stream>>>(cnt_in, bsum);
    k_scan_bsum<<<1, 512, 0, stream>>>(bsum, bpre);
    k_scan_write<<<SCAN_BLK, 256, 0, stream>>>(cnt_in, cnt_out, bpre, row_start, cursor, dn_out, dn_in);
    k_fill<<<(N_EDGES + 255) / 256, 256, 0, stream>>>(src, dst, cursor, csr_src);

    // layer 0
    k_gemm0<<<512, 256, 0, stream>>>(feats, Wt0, br0, dn_out, Hb, B);
    k_agg<0><<<N_NODES / 4, 256, 0, stream>>>(row_start, csr_src, Hb, dn_in, b0, B);
    k_stats_partial<<<SB, 256, 0, stream>>>(B, psum, psumsq);
    k_stats_final<<<1, 64, 0, stream>>>(psum, psumsq, g0, be0, scale0, shift0);
    k_norm1<<<(N_NODES * HID) / 256, 256, 0, stream>>>(scale0, shift0, dn_out, B, Hb);

    // layer 1
    k_agg<1><<<N_NODES / 4, 256, 0, stream>>>(row_start, csr_src, Hb, dn_in, nullptr, C);
    k_gemm1<<<512, 256, 0, stream>>>(C, B, Wt1, b1, br1, C);
    k_stats_partial<<<SB, 256, 0, stream>>>(C, psum, psumsq);
    k_stats_final<<<1, 64, 0, stream>>>(psum, psumsq, g1, be1, scale1, shift1);

    // head
    k_final<<<N_GRAPHS, 64, 0, stream>>>(offsets, C, scale1, shift1, Wl, bl, out);
}